// Round 13
// baseline (404.621 us; speedup 1.0000x reference)
//
#include <hip/hip_runtime.h>

// ---- problem constants ----
constexpr int B_  = 128;
constexpr int T_  = 24;
constexpr int E_  = 512;
constexpr int H_  = 512;
constexpr int V_  = 10000;
constexpr int G4  = 2048;   // 4*H
constexpr int TP1 = 25;     // T+1
constexpr int NTILES = 1896; // 24 t-tiles x 79 n-tiles (128x128 logits)

typedef __attribute__((ext_vector_type(8))) short bf16x8;   // 8 bf16 = 4 VGPR
typedef __attribute__((ext_vector_type(4))) short short4v;  // 4 bf16 = 8 B
typedef __attribute__((ext_vector_type(4))) float f32x4;

#define MFMA_16x16x32_BF16(a, b, c) __builtin_amdgcn_mfma_f32_16x16x32_bf16((a), (b), (c), 0, 0, 0)

// fp32 -> bf16 round-to-nearest-even (bit-level, no header ABI dependence)
__device__ inline unsigned short f2bf(float f) {
    unsigned int u = __float_as_uint(f);
    unsigned int r = (u + 0x7FFFu + ((u >> 16) & 1u)) >> 16;
    return (unsigned short)r;
}

// async global->LDS, 16B per lane. LDS dest must be linear-in-lane.
__device__ inline void gl16(const unsigned short* g, unsigned short* l) {
    __builtin_amdgcn_global_load_lds(
        (const __attribute__((address_space(1))) unsigned int*)g,
        (__attribute__((address_space(3))) unsigned int*)l, 16, 0, 0);
}

// LDS granule swizzle for [R][32] bf16 tiles (kept from R5 — harmless).
__device__ inline int swz16(int row, int lq) {      // returns short offset
    return (((row << 2) | lq) ^ (row & 7)) << 3;
}

// ---------------------------------------------------------------------------
// ALL prep in ONE launch: fp32->bf16 weight staging, embedding gather,
// t=0 one-hot row + length tail, flag/counter/queue reset.
// ---------------------------------------------------------------------------
__global__ __launch_bounds__(256) void k_prep(const float* __restrict__ Wih,
                                              const float* __restrict__ Whh,
                                              const float* __restrict__ Wout,
                                              const float* __restrict__ images,
                                              const float* __restrict__ Wemb,
                                              const int* __restrict__ captions,
                                              const int* __restrict__ cap_len,
                                              unsigned short* __restrict__ dWih,
                                              unsigned short* __restrict__ dWhh,
                                              unsigned short* __restrict__ dWout,
                                              unsigned short* __restrict__ dimg,
                                              unsigned short* __restrict__ Xemb,
                                              float* __restrict__ out,
                                              unsigned* __restrict__ flg,
                                              unsigned* __restrict__ cnt,
                                              int* __restrict__ queue) {
    int b = blockIdx.x;
    if (b == 0) {                                // control-state reset
        flg[threadIdx.x * 32] = 0u;              // 256 producer flags
        if (threadIdx.x < 192) cnt[threadIdx.x * 32] = 0u;   // 24t x 8mi
        if (threadIdx.x == 0) queue[0] = 0;
    }
    if (b < 7112) {                              // fp32 -> bf16 segments
        const float* src; unsigned short* dst; int i;
        if (b < 1024)      { src = Wih;    dst = dWih;  i = b * 256 + threadIdx.x; }
        else if (b < 2048) { src = Whh;    dst = dWhh;  i = (b - 1024) * 256 + threadIdx.x; }
        else if (b < 7048) { src = Wout;   dst = dWout; i = (b - 2048) * 256 + threadIdx.x; }
        else               { src = images; dst = dimg;  i = (b - 7048) * 256 + threadIdx.x; }
        float4 v = ((const float4*)src)[i];
        short4v o;
        o[0] = (short)f2bf(v.x); o[1] = (short)f2bf(v.y);
        o[2] = (short)f2bf(v.z); o[3] = (short)f2bf(v.w);
        ((short4v*)dst)[i] = o;
    } else if (b < 8648) {                       // embedding gather
        int i = (b - 7112) * 256 + threadIdx.x;  // < 393216
        int row = i >> 7;                        // m = t*128 + bb
        int k4  = i & 127;
        int bb = row & 127, t = row >> 7;
        int tok = captions[bb * T_ + t];
        short4v o = {0, 0, 0, 0};
        if (tok > 0 && tok < V_) {               // tok==0 is padding -> zeros
            float4 v = ((const float4*)(Wemb + (long)tok * E_))[k4];
            o[0] = (short)f2bf(v.x); o[1] = (short)f2bf(v.y);
            o[2] = (short)f2bf(v.z); o[3] = (short)f2bf(v.w);
        }
        ((short4v*)Xemb)[(long)row * 128 + k4] = o;
    } else {                                     // t=0 one-hot row + tail
        int idx = (b - 8648) * 256 + threadIdx.x;
        constexpr int Q = V_ / 4;                // 2500 float4 per row
        if (idx < B_ * Q) {
            int bb = idx / Q;
            int q = idx - bb * Q;
            float4 zero = {0.f, 0.f, 0.f, 0.f};
            float4 one1 = {0.f, 1.f, 0.f, 0.f};  // one-hot at v=1
            ((float4*)out)[(long)bb * (TP1 * Q) + q] = (q == 0) ? one1 : zero;
        }
        if (idx < B_)
            out[(size_t)B_ * TP1 * V_ + idx] = (float)(cap_len[idx] - 1);
    }
}

// ---------------------------------------------------------------------------
// FUSED recurrence + logits kernel. Grid = 768 blocks x 256 thr.
//  - blocks 0..255: R10's recurrence (fused x-GEMM, per-producer flags,
//    agent-atomic h exchange). NEW: Hall stored via paired agent-atomic
//    uints (cross-XCD visible within this kernel); after the per-step
//    vmcnt(0) drain, thread0 bumps cnt[t*8+MI] (8 per-MI-group counters/t).
//    After step 23, these blocks join the logits worker pool.
//  - blocks 256..767: logits workers from launch: pop tile q (t-major) from
//    an atomic queue; poll the 8 counters of tile's t == 32 each; then run
//    the proven R5 128x128 LDS-staged tile.
// DEADLOCK-FREE BY CAPACITY: 768 blocks = 3/CU; LDS 33KB (3x33<=160KB),
// __launch_bounds__(256,3) caps VGPR <= 170 -> all 768 co-resident
// regardless of dispatch order, so polls always make progress.
// ---------------------------------------------------------------------------
__global__ __launch_bounds__(256, 3) void k_main(const unsigned short* __restrict__ Xemb,
                                                 const unsigned short* __restrict__ h0,
                                                 unsigned* __restrict__ hx0,
                                                 unsigned* __restrict__ hx1,
                                                 unsigned short* __restrict__ Hall,
                                                 const unsigned short* __restrict__ Whh,
                                                 const unsigned short* __restrict__ Wih,
                                                 const float* __restrict__ bih,
                                                 const float* __restrict__ bhh,
                                                 unsigned* __restrict__ flg,
                                                 unsigned* __restrict__ cnt,
                                                 int* __restrict__ queue,
                                                 const unsigned short* __restrict__ Wout,
                                                 const float* __restrict__ bout,
                                                 float* __restrict__ out) {
    __shared__ char smem[32768];
    __shared__ int qs;
    unsigned* HallU = (unsigned*)Hall;

    if (blockIdx.x < 256) {
        // =================== recurrence role (R10 structure) ===============
        float (*part)[4][64] = (float(*)[4][64])smem;    // [16][4][64]
        int w    = threadIdx.x >> 6;
        int lane = threadIdx.x & 63;
        int lm = lane & 15, lq = lane >> 4;
        int MI = blockIdx.x >> 5;                // 0..7
        int HG = blockIdx.x & 31;                // 0..31
        int hcol = HG * 16 + lm;
        int ks = w * 128;
        int brow = MI * 16 + lq * 4 + w;
        unsigned* myFlg = flg + (MI * 32 + HG) * 32;
        unsigned* wFlg  = flg + (MI * 32 + (w << 3)) * 32;

        bf16x8 bw[4][4], wv[4][4];
        #pragma unroll
        for (int g = 0; g < 4; g++)
            #pragma unroll
            for (int kk = 0; kk < 4; kk++) {
                size_t off = (size_t)(g * 512 + hcol) * 512 + ks + kk * 32 + lq * 8;
                bw[g][kk] = *(const bf16x8*)((const short*)Whh + off);
                wv[g][kk] = *(const bf16x8*)((const short*)Wih + off);
            }
        float bs0 = bih[0 * 512 + hcol] + bhh[0 * 512 + hcol];
        float bs1 = bih[1 * 512 + hcol] + bhh[1 * 512 + hcol];
        float bs2 = bih[2 * 512 + hcol] + bhh[2 * 512 + hcol];
        float bs3 = bih[3 * 512 + hcol] + bhh[3 * 512 + hcol];
        float cp = 0.f;

        for (int t = 0; t < T_; t++) {
            const unsigned short* X = Xemb + ((size_t)(t * 128 + MI * 16 + lm)) * 512 + ks;
            bf16x8 xa[4];
            #pragma unroll
            for (int kk = 0; kk < 4; kk++)
                xa[kk] = *(const bf16x8*)(X + kk * 32 + lq * 8);

            f32x4 acc[4] = {};
            #pragma unroll
            for (int kk = 0; kk < 4; kk++) {
                acc[0] = MFMA_16x16x32_BF16(xa[kk], wv[0][kk], acc[0]);
                acc[1] = MFMA_16x16x32_BF16(xa[kk], wv[1][kk], acc[1]);
                acc[2] = MFMA_16x16x32_BF16(xa[kk], wv[2][kk], acc[2]);
                acc[3] = MFMA_16x16x32_BF16(xa[kk], wv[3][kk], acc[3]);
            }

            bf16x8 a[4];
            if (t == 0) {
                const unsigned short* A = h0 + (size_t)(MI * 16 + lm) * 512 + ks;
                #pragma unroll
                for (int kk = 0; kk < 4; kk++)
                    a[kk] = *(const bf16x8*)(A + kk * 32 + lq * 8);
            } else {
                if (lane < 8) {
                    unsigned want = (unsigned)t;
                    while (__hip_atomic_load(wFlg + lane * 32, __ATOMIC_RELAXED,
                                             __HIP_MEMORY_SCOPE_AGENT) < want)
                        __builtin_amdgcn_s_sleep(1);
                }
                __builtin_amdgcn_wave_barrier();
                asm volatile("" ::: "memory");
                const unsigned long long* A = (const unsigned long long*)
                    (((t & 1) ? hx1 : hx0) + ((size_t)(MI * 16 + lm) * 512 + ks) / 2);
                #pragma unroll
                for (int kk = 0; kk < 4; kk++) {
                    union { unsigned long long q[2]; bf16x8 v; } cv;
                    cv.q[0] = __hip_atomic_load(A + kk * 8 + lq * 2,
                                                __ATOMIC_RELAXED, __HIP_MEMORY_SCOPE_AGENT);
                    cv.q[1] = __hip_atomic_load(A + kk * 8 + lq * 2 + 1,
                                                __ATOMIC_RELAXED, __HIP_MEMORY_SCOPE_AGENT);
                    a[kk] = cv.v;
                }
            }

            #pragma unroll
            for (int kk = 0; kk < 4; kk++) {
                acc[0] = MFMA_16x16x32_BF16(a[kk], bw[0][kk], acc[0]);
                acc[1] = MFMA_16x16x32_BF16(a[kk], bw[1][kk], acc[1]);
                acc[2] = MFMA_16x16x32_BF16(a[kk], bw[2][kk], acc[2]);
                acc[3] = MFMA_16x16x32_BF16(a[kk], bw[3][kk], acc[3]);
            }

            #pragma unroll
            for (int g = 0; g < 4; g++)
                #pragma unroll
                for (int r = 0; r < 4; r++)
                    part[g * 4 + r][w][lane] = acc[g][r];
            __syncthreads();

            float gi = part[0*4+w][0][lane] + part[0*4+w][1][lane] + part[0*4+w][2][lane] + part[0*4+w][3][lane] + bs0;
            float gf = part[1*4+w][0][lane] + part[1*4+w][1][lane] + part[1*4+w][2][lane] + part[1*4+w][3][lane] + bs1;
            float gg = part[2*4+w][0][lane] + part[2*4+w][1][lane] + part[2*4+w][2][lane] + part[2*4+w][3][lane] + bs2;
            float go = part[3*4+w][0][lane] + part[3*4+w][1][lane] + part[3*4+w][2][lane] + part[3*4+w][3][lane] + bs3;
            float si = 1.f / (1.f + expf(-gi));
            float sf = 1.f / (1.f + expf(-gf));
            float so = 1.f / (1.f + expf(-go));
            float cn = sf * cp + si * tanhf(gg);
            float hn = so * tanhf(cn);
            cp = cn;
            unsigned short hb = f2bf(hn);

            // paired agent stores: h exchange (t<23) + Hall (always)
            unsigned hb1 = (unsigned short)__shfl_down((int)hb, 1);
            unsigned pv = (unsigned)hb | (hb1 << 16);
            if (!(lm & 1)) {
                if (t < T_ - 1) {
                    unsigned* HW = (t & 1) ? hx0 : hx1;
                    __hip_atomic_store(HW + (brow * 512 + hcol) / 2, pv,
                                       __ATOMIC_RELAXED, __HIP_MEMORY_SCOPE_AGENT);
                }
                __hip_atomic_store(HallU + ((size_t)t * 65536 + (size_t)brow * 512 + hcol) / 2,
                                   pv, __ATOMIC_RELAXED, __HIP_MEMORY_SCOPE_AGENT);
            }
            asm volatile("s_waitcnt vmcnt(0)" ::: "memory");
            __syncthreads();
            if (threadIdx.x == 0) {
                if (t < T_ - 1)
                    __hip_atomic_store(myFlg, (unsigned)(t + 1), __ATOMIC_RELAXED,
                                       __HIP_MEMORY_SCOPE_AGENT);
                __hip_atomic_fetch_add(cnt + ((t << 3) + MI) * 32, 1u,
                                       __ATOMIC_RELAXED, __HIP_MEMORY_SCOPE_AGENT);
            }
        }
        __syncthreads();                         // done with part[] -> reuse as tiles
    }

    // ======================= logits worker pool ===========================
    {
        unsigned short* ldsA0 = (unsigned short*)smem;           // [2][4096]
        unsigned short* ldsB0 = (unsigned short*)(smem + 16384); // [2][4096]
        int i = threadIdx.x;
        int w = i >> 6, lane = i & 63;
        int lm = lane & 15, lq = lane >> 4;
        int wr = w >> 1, wc = w & 1;
        int mm0 = ((i >> 2) & 7) ^ ((i >> 4) & 1);   // writer inverse swizzle
        int li  = i ^ mm0;
        unsigned short* lA = ldsA0 + i * 8;
        unsigned short* lB = ldsB0 + i * 8;

        for (;;) {
            if (threadIdx.x == 0) qs = atomicAdd(queue, 1);
            __syncthreads();
            int q = qs;
            if (q >= NTILES) break;
            int MI = q / 79;                     // == timestep t
            int NI = q - MI * 79;

            // readiness: all 8 MI-groups completed step MI (8 x 32 blocks)
            if (threadIdx.x < 8) {
                while (__hip_atomic_load(cnt + ((MI << 3) + threadIdx.x) * 32,
                                         __ATOMIC_RELAXED, __HIP_MEMORY_SCOPE_AGENT) < 32u)
                    __builtin_amdgcn_s_sleep(16);
            }
            __syncthreads();

            const unsigned short* gA = Hall + (size_t)(MI * 128 + (li >> 2)) * 512 + (li & 3) * 8;
            const unsigned short* gB = Wout + (size_t)(NI * 128 + (li >> 2)) * 512 + (li & 3) * 8;

            f32x4 acc[4][4] = {};
            {   // stage(0, 0)
                gl16(gA,            lA);
                gl16(gA + 64 * 512, lA + 2048);
                gl16(gB,            lB);
                gl16(gB + 64 * 512, lB + 2048);
            }
            for (int ksi = 0; ksi < 16; ksi++) {
                int cur = ksi & 1;
                if (ksi < 15) {                  // stage(cur^1, ksi+1)
                    int go = (ksi + 1) * 32;
                    int bo = (cur ^ 1) * 4096;
                    gl16(gA + go,            lA + bo);
                    gl16(gA + go + 64 * 512, lA + bo + 2048);
                    gl16(gB + go,            lB + bo);
                    gl16(gB + go + 64 * 512, lB + bo + 2048);
                }
                __syncthreads();
                bf16x8 af[4], bfr[4];
                #pragma unroll
                for (int mi = 0; mi < 4; mi++)
                    af[mi] = *(const bf16x8*)&ldsA0[cur * 4096 + swz16(wr * 64 + mi * 16 + lm, lq)];
                #pragma unroll
                for (int ni = 0; ni < 4; ni++)
                    bfr[ni] = *(const bf16x8*)&ldsB0[cur * 4096 + swz16(wc * 64 + ni * 16 + lm, lq)];
                #pragma unroll
                for (int mi = 0; mi < 4; mi++)
                    #pragma unroll
                    for (int ni = 0; ni < 4; ni++)
                        acc[mi][ni] = MFMA_16x16x32_BF16(af[mi], bfr[ni], acc[mi][ni]);
                __syncthreads();
            }

            #pragma unroll
            for (int mi = 0; mi < 4; mi++) {
                #pragma unroll
                for (int r = 0; r < 4; r++) {
                    int b = wr * 64 + mi * 16 + lq * 4 + r;
                    float* orow = out + ((size_t)b * TP1 + MI + 1) * V_;
                    #pragma unroll
                    for (int ni = 0; ni < 4; ni++) {
                        int n = NI * 128 + wc * 64 + ni * 16 + lm;
                        if (n < V_) orow[n] = acc[mi][ni][r] + bout[n];
                    }
                }
            }
        }
    }
}

// ---------------------------------------------------------------------------
extern "C" void kernel_launch(void* const* d_in, const int* in_sizes, int n_in,
                              void* d_out, int out_size, void* d_ws, size_t ws_size,
                              hipStream_t stream) {
    const float* images   = (const float*)d_in[0];
    const int*   captions = (const int*)d_in[1];
    const int*   cap_len  = (const int*)d_in[2];
    const float* Wemb     = (const float*)d_in[3];
    const float* Wih      = (const float*)d_in[4];
    const float* Whh      = (const float*)d_in[5];
    const float* bih      = (const float*)d_in[6];
    const float* bhh      = (const float*)d_in[7];
    const float* Wout     = (const float*)d_in[8];
    const float* bout     = (const float*)d_in[9];
    float* out = (float*)d_out;

    // workspace layout (all offsets multiples of 256B)
    char* ws = (char*)d_ws;
    unsigned short* Wih_bf  = (unsigned short*)(ws);             //  2,097,152
    unsigned short* Whh_bf  = (unsigned short*)(ws + 2097152);   //  2,097,152
    unsigned short* Wout_bf = (unsigned short*)(ws + 4194304);   // 10,240,000
    unsigned short* Xemb    = (unsigned short*)(ws + 14434304);  //  3,145,728
    unsigned short* Hall    = (unsigned short*)(ws + 17580032);  //  3,145,728
    unsigned short* h0      = (unsigned short*)(ws + 20725760);  //    131,072
    unsigned*       hx0     = (unsigned*)(ws + 20856832);        //    131,072
    unsigned*       hx1     = (unsigned*)(ws + 20987904);        //    131,072
    unsigned*       flg     = (unsigned*)(ws + 21118976);        //     32,768
    unsigned*       cnt     = (unsigned*)(ws + 21151744);        //     24,576
    int*            queue   = (int*)(ws + 21176320);             //        256

    // ALL prep in one launch (staging + embed + start + control reset)
    k_prep<<<9898, 256, 0, stream>>>(Wih, Whh, Wout, images, Wemb, captions,
                                     cap_len, Wih_bf, Whh_bf, Wout_bf, h0,
                                     Xemb, out, flg, cnt, queue);

    // fused recurrence + overlapped logits (768 blocks, all co-resident)
    k_main<<<768, 256, 0, stream>>>(Xemb, h0, hx0, hx1, Hall, Whh_bf, Wih_bf,
                                    bih, bhh, flg, cnt, queue,
                                    Wout_bf, bout, out);
}